// Round 11
// baseline (282.314 us; speedup 1.0000x reference)
//
#include <hip/hip_runtime.h>
#include <hip/hip_bf16.h>

#define D_MODEL 1024
#define NHEAD 16
#define DK 64
#define B_ 4
#define S_ 2048
#define ROWS (B_*S_)          // 8192
#define QKV_N (3*D_MODEL)     // 3072
#define SM_C 0.18033688011112042f   // 0.125 * log2(e), folded into Wq

typedef __attribute__((ext_vector_type(4))) float f32x4;
typedef __attribute__((ext_vector_type(8))) short bf16x8;
typedef unsigned short u16;
typedef unsigned int u32;

__device__ __forceinline__ u16 f2bf(float f) {
    union { float f; u32 u; } x; x.f = f;
    u32 r = x.u + 0x7fffu + ((x.u >> 16) & 1u);
    return (u16)(r >> 16);
}
__device__ __forceinline__ float bf2f(u16 h) {
    union { u32 u; float f; } x; x.u = ((u32)h) << 16;
    return x.f;
}
__device__ __forceinline__ u32 pk2bf(float a, float b) {
    union { __hip_bfloat162 h; u32 u; } c;
    c.h = __float22bfloat162_rn(float2{a, b});
    return c.u;
}

// async global->LDS, 16B per lane.
__device__ __forceinline__ void gload_lds16(const void* g, void* l) {
    __builtin_amdgcn_global_load_lds(
        (const __attribute__((address_space(1))) u32*)g,
        (__attribute__((address_space(3))) u32*)l, 16, 0, 0);
}

// All five f32->bf16 casts + the RoPE cos/sin table in ONE launch
// (region-dispatched by blockIdx).
// Wq is PRE-SCALED by SM_C: Q = x*(C*Wq) = C*(x*Wq) -> softmax needs no
// scale; the uniform 2^T offset cancels in O = (P V)/l and is dropped.
__global__ void cast_all(const float* __restrict__ x,
                         const float* __restrict__ wq, const float* __restrict__ wk,
                         const float* __restrict__ wv, const float* __restrict__ wo,
                         u16* __restrict__ xb, u16* __restrict__ wqkvb, u16* __restrict__ wob,
                         const int* __restrict__ pos, float2* __restrict__ tab) {
    int bi = blockIdx.x;
    if (bi >= 12288) {        // RoPE table: tab[s][i] = {cos,sin}(pos[s]*10000^(-i/32))
        int idx = (bi - 12288) * 256 + (int)threadIdx.x;   // 0..65535
        int s = idx >> 5, i = idx & 31;
        float invf = __expf(-(float)i * 0.2878231366242557f);
        float ang = (float)pos[s] * invf;
        float sn, cs;
        sincosf(ang, &sn, &cs);
        tab[idx] = float2{cs, sn};
        return;
    }
    const float* src; u16* dst; int local; float scale = 1.0f;
    if (bi < 8192)       { src = x;  dst = xb;               local = bi; }
    else if (bi < 9216)  { src = wq; dst = wqkvb;            local = bi - 8192; scale = SM_C; }
    else if (bi < 10240) { src = wk; dst = wqkvb + 1048576;  local = bi - 9216; }
    else if (bi < 11264) { src = wv; dst = wqkvb + 2097152;  local = bi - 10240; }
    else                 { src = wo; dst = wob;              local = bi - 11264; }
    int i = (local * 256 + (int)threadIdx.x) * 4;
    float4 v = *(const float4*)(src + i);
    ushort4 o;
    o.x = f2bf(v.x * scale); o.y = f2bf(v.y * scale);
    o.z = f2bf(v.z * scale); o.w = f2bf(v.w * scale);
    *(ushort4*)(dst + i) = o;
}

// C[m,n] = sum_k A[m,k] * B[n,k];  A:[M,K] bf16, B:[N,K] bf16 (both row-major)
// T1: XCD-chunked block swizzle (nwg % 8 == 0 at both call sites: 1536, 512).
// Round-11: BK=64 + both-sides XOR swizzle (r10, proven) PLUS 2-buffer
// issue-early/wait-late staging (r8's mechanism): per K-step,
//   vmcnt(0) [cheap: these loads were issued one iteration ago and their
//   latency hid under 32 MFMA + ds_reads]; s_barrier; STG(t+1, other buf);
//   compute(t).
// One barrier per K-step (16 total). STG(t+1) overwrites the buffer read at
// t-1: safe because a wave issues it only after the top-of-t barrier, which
// it reaches only after its t-1 ds_reads were consumed by MFMAs (compiler
// lgkm waits) -- same discipline as the r8 kernel that passed refcheck.
// Accumulation order bitwise-identical to r10 (kk-outer over same 32-chunks).
// MODE 0: fp32 C.  MODE 1: bf16 C with RoPE fused into the epilogue for
// columns < 2048 (Q,K regions). cos/sin from the precomputed table.
template<int MODE>
__global__ __launch_bounds__(256, 2)
void gemm_bt(const u16* __restrict__ A, const u16* __restrict__ Bm,
             void* __restrict__ Cp, int M, int N, int K,
             const float2* __restrict__ tab) {
    extern __shared__ u16 ldsb[];   // 2 bufs x (A 8192 + B 8192) u16 = 64 KB
    const int tid = threadIdx.x;
    const int lane = tid & 63, wave = tid >> 6;
    const int gx = gridDim.x;
    const int nwg = gx * gridDim.y;
    int lin = blockIdx.y * gx + blockIdx.x;
    int nl = (lin & 7) * (nwg >> 3) + (lin >> 3);
    const int m0 = (nl / gx) * 128, n0 = (nl % gx) * 128;
    const int wm = (wave >> 1) * 64, wn = (wave & 1) * 64;
    const int q4 = lane >> 4, c16 = lane & 15;
    f32x4 acc[4][4] = {};

    // Staging (r10-proven): dst byte d = p*4096 + tid*16 -> row = p*32+(tid>>3),
    // chunk = tid&7; pre-swizzled source col = ((tid&7) ^ ((tid>>3)&7)) * 8.
    const int srow = tid >> 3;
    const int scol = ((tid & 7) ^ (srow & 7)) * 8;
    // Read-side swizzle (row&7 == c16&7 since wm/wn, mt*16 are multiples of 8):
    const int rsw = (c16 & 7) << 4;

#define STG(t_, sp_) do { \
    u16* Ad_ = ldsb + (sp_) * 16384; \
    u16* Bd_ = Ad_ + 8192; \
    const int k0_ = (t_) * 64; \
    _Pragma("unroll") \
    for (int p = 0; p < 4; ++p) { \
        gload_lds16(A + (size_t)(m0 + p * 32 + srow) * K + k0_ + scol, \
                    (char*)Ad_ + p * 4096 + tid * 16); \
        gload_lds16(Bm + (size_t)(n0 + p * 32 + srow) * K + k0_ + scol, \
                    (char*)Bd_ + p * 4096 + tid * 16); \
    } \
} while (0)

    const int NT = K >> 6;      // 16 for K=1024
    STG(0, 0);
    int cur = 0;
    for (int t = 0; t < NT; ++t) {
        asm volatile("s_waitcnt vmcnt(0)" ::: "memory");   // t's loads landed
        __builtin_amdgcn_s_barrier();                      // all waves certify
        asm volatile("" ::: "memory");
        if (t + 1 < NT) STG(t + 1, cur ^ 1);               // issue-early for t+1
        const u16* As_ = ldsb + cur * 16384;
        const u16* Bs_ = As_ + 8192;
        #pragma unroll
        for (int kk = 0; kk < 2; ++kk) {
            bf16x8 af[4], bf[4];
            #pragma unroll
            for (int mt = 0; mt < 4; ++mt)
                af[mt] = *(const bf16x8*)((const char*)As_ + (wm + mt * 16 + c16) * 128
                                          + ((kk * 64 + q4 * 16) ^ rsw));
            #pragma unroll
            for (int nt = 0; nt < 4; ++nt)
                bf[nt] = *(const bf16x8*)((const char*)Bs_ + (wn + nt * 16 + c16) * 128
                                          + ((kk * 64 + q4 * 16) ^ rsw));
            #pragma unroll
            for (int mt = 0; mt < 4; ++mt)
                #pragma unroll
                for (int nt = 0; nt < 4; ++nt)
                    acc[mt][nt] = __builtin_amdgcn_mfma_f32_16x16x32_bf16(af[mt], bf[nt], acc[mt][nt], 0, 0, 0);
        }
        cur ^= 1;
    }
#undef STG

    const bool doRope = (MODE == 1) && (n0 < 2048);   // block-uniform
    int ti[4];
    #pragma unroll
    for (int nt = 0; nt < 4; ++nt)
        ti[nt] = ((n0 + wn + nt * 16 + c16) >> 1) & 31;

    #pragma unroll
    for (int mt = 0; mt < 4; ++mt)
        #pragma unroll
        for (int r = 0; r < 4; ++r) {
            const int row = m0 + wm + mt * 16 + q4 * 4 + r;
            float sn[4], cs[4];
            if (doRope) {
                const float2* trow = tab + (size_t)(row & (S_ - 1)) * 32;
                #pragma unroll
                for (int nt = 0; nt < 4; ++nt) {
                    float2 t = trow[ti[nt]];
                    cs[nt] = t.x; sn[nt] = t.y;
                }
            }
            #pragma unroll
            for (int nt = 0; nt < 4; ++nt) {
                const int col = n0 + wn + nt * 16 + c16;
                float v = acc[mt][nt][r];
                if (doRope) {
                    const float partner = __shfl_xor(v, 1, 64);
                    // even col: v = xe, partner = xo -> re = cos*xe - sin*xo
                    // odd  col: v = xo, partner = xe -> ro = sin*xe + cos*xo
                    v = (c16 & 1) ? __builtin_fmaf(sn[nt], partner, cs[nt] * v)
                                  : __builtin_fmaf(cs[nt], v, -sn[nt] * partner);
                }
                if (MODE == 1) ((u16*)Cp)[(size_t)row * N + col] = f2bf(v);
                else           ((float*)Cp)[(size_t)row * N + col] = v;
            }
        }
}

// Balanced schedule: 12 groups per bh, each exactly 44 processes.
__device__ __constant__ signed char g_pairs[32] = {
    11,31, 12,30, 13,29, 14,28, 15,27, 16,26, 17,25, 18,24, 19,23, 20,22,
    10,21, 0,9,  7,8,  5,6,  3,4,  1,2 };
__device__ __constant__ unsigned char g_poff[13] = {0,1,2,3,4,5,6,7,8,9,10,12,16};

// Softmax, no scale/offset: Q pre-scaled by C at cast time; uniform 2^T
// offset cancels in O = (P V)/l. p = exp2(s'), s' <= ~46 -> p <= 8e13 (fp32
// safe); masked entries exp2(-1e30) = 0. Per-lane l partials.
__device__ __forceinline__ void softmax_p(
    f32x4 (&sf)[4], u16* __restrict__ Psw, float& l_i,
    int qrow0, int kt, bool diag, int c16, int q4, bf16x8 (&pf)[2]) {
    if (diag) {
        const int qg = qrow0 + c16;
        #pragma unroll
        for (int nt = 0; nt < 4; ++nt)
            #pragma unroll
            for (int r = 0; r < 4; ++r) {
                int kg = kt * 64 + nt * 16 + q4 * 4 + r;
                if (kg > qg) sf[nt][r] = -1e30f;
            }
    }
    float rs = 0.f;
    #pragma unroll
    for (int nt = 0; nt < 4; ++nt) {
        float p0 = exp2f(sf[nt][0]);
        float p1 = exp2f(sf[nt][1]);
        float p2 = exp2f(sf[nt][2]);
        float p3 = exp2f(sf[nt][3]);
        rs += (p0 + p1) + (p2 + p3);
        uint2 w; w.x = pk2bf(p0, p1); w.y = pk2bf(p2, p3);
        *(uint2*)&Psw[c16 * 72 + nt * 16 + q4 * 4] = w;   // P[qrow][key]
    }
    l_i += rs;
    pf[0] = *(const bf16x8*)&Psw[c16 * 72 + q4 * 8];
    pf[1] = *(const bf16x8*)&Psw[c16 * 72 + 32 + q4 * 8];
}

// Flash attention (unchanged: merged strips, DMA-K with XOR swizzle,
// XCD-chunked grid, per-strip Ps).
__global__ __launch_bounds__(256, 3)
void attn_kernel(const u16* __restrict__ QKV, u16* __restrict__ O) {
    __shared__ u16 Kt[2][64 * 64];
    __shared__ u16 Vt[2][64 * 72];
    __shared__ u16 Ps[8][16 * 72];    // [wave] strip A, [wave+4] strip B
    __shared__ float aS[4][16];
    const int tid = threadIdx.x, lane = tid & 63, wave = tid >> 6;
    const int q4 = lane >> 4, c16 = lane & 15;
    int lin = blockIdx.y * 12 + blockIdx.x;
    int nl = (lin & 7) * 96 + (lin >> 3);
    const int g = nl % 12;
    const int bh = nl / 12;
    const int b = bh >> 4, h = bh & 15;
    const size_t rowbase = (size_t)b * S_ * QKV_N;

    const int kr0 = wave * 16 + (lane >> 3);
    const int kcsw = ((lane & 7) ^ (lane >> 3)) * 8;
    const u16* ksrc0 = QKV + rowbase + (size_t)kr0 * QKV_N + D_MODEL + h * 64 + kcsw;
    const int ksw = (c16 & 7) << 4;
    const int koff0 = (q4 * 16) ^ ksw;
    const int koff1 = (64 + q4 * 16) ^ ksw;

    const int kp = tid & 31, dg = tid >> 5;
    const u16* vbase = QKV + rowbase + (size_t)(2 * kp) * QKV_N + 2 * D_MODEL + h * 64 + dg * 8;

    for (int pi = g_poff[g]; pi < g_poff[g + 1]; ++pi) {
        const int tA = g_pairs[2 * pi], tB = g_pairs[2 * pi + 1];

        bf16x8 qfA[2], qfB[2];
        {
            const u16* qa = QKV + rowbase + (size_t)(tA * 64 + wave * 16 + c16) * QKV_N + h * 64 + q4 * 8;
            qfA[0] = *(const bf16x8*)qa;
            qfA[1] = *(const bf16x8*)(qa + 32);
            const u16* qb = QKV + rowbase + (size_t)(tB * 64 + wave * 16 + c16) * QKV_N + h * 64 + q4 * 8;
            qfB[0] = *(const bf16x8*)qb;
            qfB[1] = *(const bf16x8*)(qb + 32);
        }
        f32x4 ofA[4] = {}, ofB[4] = {};
        float lA = 0.f, lB = 0.f;
        const int qrowA = tA * 64 + wave * 16;
        const int qrowB = tB * 64 + wave * 16;

        gload_lds16(ksrc0, (char*)Kt[0] + wave * 2048 + lane * 16);
        gload_lds16(ksrc0 + (size_t)8 * QKV_N, (char*)Kt[0] + wave * 2048 + 1024 + lane * 16);
        bf16x8 va = *(const bf16x8*)vbase, vb = *(const bf16x8*)(vbase + QKV_N);
        #pragma unroll
        for (int j = 0; j < 8; ++j) {
            u32 w = ((u32)(u16)va[j]) | (((u32)(u16)vb[j]) << 16);
            *(u32*)&Vt[0][(dg * 8 + j) * 72 + 2 * kp] = w;
        }
        __syncthreads();

        int bb = 0;
        for (int kt = 0; kt <= tB; ++kt) {
            const bool more = kt < tB;
            const bool aAct = kt <= tA;
            if (more) {
                const u16* s0 = ksrc0 + (size_t)(kt + 1) * 64 * QKV_N;
                gload_lds16(s0, (char*)Kt[bb ^ 1] + wave * 2048 + lane * 16);
                gload_lds16(s0 + (size_t)8 * QKV_N, (char*)Kt[bb ^ 1] + wave * 2048 + 1024 + lane * 16);
                const u16* vp_ = vbase + (size_t)(kt + 1) * 64 * QKV_N;
                va = *(const bf16x8*)vp_;  vb = *(const bf16x8*)(vp_ + QKV_N);
            }

            f32x4 sfA[4] = {}, sfB[4] = {};
            const char* Kb = (const char*)Kt[bb];
            __builtin_amdgcn_s_setprio(1);
            if (aAct) {
                #pragma unroll
                for (int nt = 0; nt < 4; ++nt) {
                    bf16x8 kf0 = *(const bf16x8*)(Kb + nt * 2048 + c16 * 128 + koff0);
                    bf16x8 kf1 = *(const bf16x8*)(Kb + nt * 2048 + c16 * 128 + koff1);
                    sfB[nt] = __builtin_amdgcn_mfma_f32_16x16x32_bf16(kf0, qfB[0], sfB[nt], 0, 0, 0);
                    sfB[nt] = __builtin_amdgcn_mfma_f32_16x16x32_bf16(kf1, qfB[1], sfB[nt], 0, 0, 0);
                    sfA[nt] = __builtin_amdgcn_mfma_f32_16x16x32_bf16(kf0, qfA[0], sfA[nt], 0, 0, 0);
                    sfA[nt] = __builtin_amdgcn_mfma_f32_16x16x32_bf16(kf1, qfA[1], sfA[nt], 0, 0, 0);
                }
            } else {
                #pragma unroll
                for (int nt = 0; nt < 4; ++nt) {
                    bf16x8 kf0 = *(const bf16x8*)(Kb + nt * 2048 + c16 * 128 + koff0);
                    bf16x8 kf1 = *(const bf16x8*)(Kb + nt * 2048 + c16 * 128 + koff1);
                    sfB[nt] = __builtin_amdgcn_mfma_f32_16x16x32_bf16(kf0, qfB[0], sfB[nt], 0, 0, 0);
                    sfB[nt] = __builtin_amdgcn_mfma_f32_16x16x32_bf16(kf1, qfB[1], sfB[nt], 0, 0, 0);
                }
            }
            __builtin_amdgcn_s_setprio(0);

            bf16x8 pfA[2], pfB[2];
            if (aAct) softmax_p(sfA, Ps[wave], lA, qrowA, kt, kt == tA, c16, q4, pfA);
            softmax_p(sfB, Ps[wave + 4], lB, qrowB, kt, kt == tB, c16, q4, pfB);

            if (more) {
                #pragma unroll
                for (int j = 0; j < 8; ++j) {
                    u32 w = ((u32)(u16)va[j]) | (((u32)(u16)vb[j]) << 16);
                    *(u32*)&Vt[bb ^ 1][(dg * 8 + j) * 72 + 2 * kp] = w;
                }
            }

            const u16* Vb = Vt[bb];
            __builtin_amdgcn_s_setprio(1);
            if (aAct) {
                #pragma unroll
                for (int kk = 0; kk < 2; ++kk)
                    #pragma unroll
                    for (int nt = 0; nt < 4; ++nt) {
                        bf16x8 vf = *(const bf16x8*)&Vb[(nt * 16 + c16) * 72 + kk * 32 + q4 * 8];
                        ofB[nt] = __builtin_amdgcn_mfma_f32_16x16x32_bf16(pfB[kk], vf, ofB[nt], 0, 0, 0);
                        ofA[nt] = __builtin_amdgcn_mfma_f32_16x16x32_bf16(pfA[kk], vf, ofA[nt], 0, 0, 0);
                    }
            } else {
                #pragma unroll
                for (int kk = 0; kk < 2; ++kk)
                    #pragma unroll
                    for (int nt = 0; nt < 4; ++nt) {
                        bf16x8 vf = *(const bf16x8*)&Vb[(nt * 16 + c16) * 72 + kk * 32 + q4 * 8];
                        ofB[nt] = __builtin_amdgcn_mfma_f32_16x16x32_bf16(pfB[kk], vf, ofB[nt], 0, 0, 0);
                    }
            }
            __builtin_amdgcn_s_setprio(0);

            __syncthreads();
            bb ^= 1;
        }

        lA += __shfl_xor(lA, 16, 64); lA += __shfl_xor(lA, 32, 64);
        lB += __shfl_xor(lB, 16, 64); lB += __shfl_xor(lB, 32, 64);
        if (q4 == 0) aS[wave][c16] = lA;
        f32x4 lv = *(const f32x4*)&aS[wave][q4 * 4];
        #pragma unroll
        for (int r = 0; r < 4; ++r) {
            float inv = 1.0f / lv[r];
            int row = b * S_ + tA * 64 + wave * 16 + q4 * 4 + r;
            #pragma unroll
            for (int nt = 0; nt < 4; ++nt)
                O[(size_t)row * D_MODEL + h * 64 + nt * 16 + c16] = f2bf(ofA[nt][r] * inv);
        }
        if (q4 == 0) aS[wave][c16] = lB;
        f32x4 lv2 = *(const f32x4*)&aS[wave][q4 * 4];
        #pragma unroll
        for (int r = 0; r < 4; ++r) {
            float inv = 1.0f / lv2[r];
            int row = b * S_ + tB * 64 + wave * 16 + q4 * 4 + r;
            #pragma unroll
            for (int nt = 0; nt < 4; ++nt)
                O[(size_t)row * D_MODEL + h * 64 + nt * 16 + c16] = f2bf(ofB[nt][r] * inv);
        }
    }
}

extern "C" void kernel_launch(void* const* d_in, const int* in_sizes, int n_in,
                              void* d_out, int out_size, void* d_ws, size_t ws_size,
                              hipStream_t stream) {
    const float* x  = (const float*)d_in[0];
    const int*   tp = (const int*)d_in[1];
    const float* Wq = (const float*)d_in[2];
    const float* Wk = (const float*)d_in[3];
    const float* Wv = (const float*)d_in[4];
    const float* Wo = (const float*)d_in[5];
    float* out = (float*)d_out;

    char* ws = (char*)d_ws;
    u16* xb    = (u16*)(ws);                 // 16,777,216 B
    u16* Wqkvb = (u16*)(ws + 16777216);      //  6,291,456 B
    u16* Wob   = (u16*)(ws + 23068672);      //  2,097,152 B
    u16* QKV   = (u16*)(ws + 25165824);      // 50,331,648 B
    u16* Ob    = (u16*)(ws + 75497472);      // 16,777,216 B  (total 92,274,688 B)
    // RoPE table lives in the first 512 KB of the Ob region: it is consumed
    // only by the qkv GEMM epilogue, which completes before attn writes Ob.
    float2* tab = (float2*)(ws + 75497472);

    static bool attr_set = false;
    if (!attr_set) {
        hipFuncSetAttribute((const void*)gemm_bt<1>,
                            hipFuncAttributeMaxDynamicSharedMemorySize, 65536);
        hipFuncSetAttribute((const void*)gemm_bt<0>,
                            hipFuncAttributeMaxDynamicSharedMemorySize, 65536);
        attr_set = true;
    }

    cast_all<<<dim3(12544), dim3(256), 0, stream>>>(x, Wq, Wk, Wv, Wo,
                                                    xb, Wqkvb, Wob, tp, tab);

    // qkv projection with fused RoPE in the epilogue.
    gemm_bt<1><<<dim3(QKV_N / 128, ROWS / 128), dim3(256), 65536, stream>>>(
        xb, Wqkvb, (void*)QKV, ROWS, QKV_N, D_MODEL, tab);

    attn_kernel<<<dim3(12, B_ * NHEAD), dim3(256), 0, stream>>>(QKV, Ob);

    gemm_bt<0><<<dim3(D_MODEL / 128, ROWS / 128), dim3(256), 65536, stream>>>(
        Ob, Wob, (void*)out, ROWS, D_MODEL, D_MODEL, nullptr);
}

// Round 12
// 262.269 us; speedup vs baseline: 1.0764x; 1.0764x over previous
//
#include <hip/hip_runtime.h>
#include <hip/hip_bf16.h>

#define D_MODEL 1024
#define NHEAD 16
#define DK 64
#define B_ 4
#define S_ 2048
#define ROWS (B_*S_)          // 8192
#define QKV_N (3*D_MODEL)     // 3072
#define SM_C 0.18033688011112042f   // 0.125 * log2(e), folded into Wq

typedef __attribute__((ext_vector_type(4))) float f32x4;
typedef __attribute__((ext_vector_type(8))) short bf16x8;
typedef unsigned short u16;
typedef unsigned int u32;

__device__ __forceinline__ u16 f2bf(float f) {
    union { float f; u32 u; } x; x.f = f;
    u32 r = x.u + 0x7fffu + ((x.u >> 16) & 1u);
    return (u16)(r >> 16);
}
__device__ __forceinline__ float bf2f(u16 h) {
    union { u32 u; float f; } x; x.u = ((u32)h) << 16;
    return x.f;
}
__device__ __forceinline__ u32 pk2bf(float a, float b) {
    union { __hip_bfloat162 h; u32 u; } c;
    c.h = __float22bfloat162_rn(float2{a, b});
    return c.u;
}

// async global->LDS, 16B per lane.
__device__ __forceinline__ void gload_lds16(const void* g, void* l) {
    __builtin_amdgcn_global_load_lds(
        (const __attribute__((address_space(1))) u32*)g,
        (__attribute__((address_space(3))) u32*)l, 16, 0, 0);
}

// All five f32->bf16 casts + the RoPE cos/sin table in ONE launch
// (region-dispatched by blockIdx).
// Wq is PRE-SCALED by SM_C: Q = x*(C*Wq) = C*(x*Wq) -> softmax needs no
// scale; the uniform 2^T offset cancels in O = (P V)/l and is dropped.
__global__ void cast_all(const float* __restrict__ x,
                         const float* __restrict__ wq, const float* __restrict__ wk,
                         const float* __restrict__ wv, const float* __restrict__ wo,
                         u16* __restrict__ xb, u16* __restrict__ wqkvb, u16* __restrict__ wob,
                         const int* __restrict__ pos, float2* __restrict__ tab) {
    int bi = blockIdx.x;
    if (bi >= 12288) {        // RoPE table: tab[s][i] = {cos,sin}(pos[s]*10000^(-i/32))
        int idx = (bi - 12288) * 256 + (int)threadIdx.x;   // 0..65535
        int s = idx >> 5, i = idx & 31;
        float invf = __expf(-(float)i * 0.2878231366242557f);
        float ang = (float)pos[s] * invf;
        float sn, cs;
        sincosf(ang, &sn, &cs);
        tab[idx] = float2{cs, sn};
        return;
    }
    const float* src; u16* dst; int local; float scale = 1.0f;
    if (bi < 8192)       { src = x;  dst = xb;               local = bi; }
    else if (bi < 9216)  { src = wq; dst = wqkvb;            local = bi - 8192; scale = SM_C; }
    else if (bi < 10240) { src = wk; dst = wqkvb + 1048576;  local = bi - 9216; }
    else if (bi < 11264) { src = wv; dst = wqkvb + 2097152;  local = bi - 10240; }
    else                 { src = wo; dst = wob;              local = bi - 11264; }
    int i = (local * 256 + (int)threadIdx.x) * 4;
    float4 v = *(const float4*)(src + i);
    ushort4 o;
    o.x = f2bf(v.x * scale); o.y = f2bf(v.y * scale);
    o.z = f2bf(v.z * scale); o.w = f2bf(v.w * scale);
    *(ushort4*)(dst + i) = o;
}

// C[m,n] = sum_k A[m,k] * B[n,k];  A:[M,K] bf16, B:[N,K] bf16 (both row-major)
// T1: XCD-chunked block swizzle (nwg % 8 == 0 at both call sites: 1536, 512).
// BK=64, SINGLE 32KB LDS buffer, 2 barriers per K-step (16 steps). This is
// the occupancy-optimal point of this structure: 32KB -> ~5 blocks/CU, and
// cross-block TLP hides the per-step staging drain. Measured across this
// session: 48KB 3-buf counted-vmcnt (r8/r9) and 64KB 2-buf issue-early (r11)
// both LOSE to this (occupancy drop > overlap gain). Do not grow LDS.
// Rows are 128B strided -> both-sides XOR involution byte ^= ((row&7)<<4)
// (pre-swizzled DMA source, swizzled ds_read), proven in attn-K.
// MODE 0: fp32 C.  MODE 1: bf16 C with RoPE fused into the epilogue for
// columns < 2048 (Q,K regions). cos/sin from the precomputed table.
template<int MODE>
__global__ __launch_bounds__(256, 2)
void gemm_bt(const u16* __restrict__ A, const u16* __restrict__ Bm,
             void* __restrict__ Cp, int M, int N, int K,
             const float2* __restrict__ tab) {
    __shared__ u16 As[128 * 64];   // 16 KB, row stride 128 B, XOR-swizzled
    __shared__ u16 Bs[128 * 64];   // 16 KB
    const int tid = threadIdx.x;
    const int lane = tid & 63, wave = tid >> 6;
    const int gx = gridDim.x;
    const int nwg = gx * gridDim.y;
    int lin = blockIdx.y * gx + blockIdx.x;
    int nl = (lin & 7) * (nwg >> 3) + (lin >> 3);
    const int m0 = (nl / gx) * 128, n0 = (nl % gx) * 128;
    const int wm = (wave >> 1) * 64, wn = (wave & 1) * 64;
    const int q4 = lane >> 4, c16 = lane & 15;
    f32x4 acc[4][4] = {};

    // Staging: thread covers 4x16B per matrix per tile; dst byte
    // d = p*4096 + tid*16 -> row = p*32 + (tid>>3), in-row chunk = tid&7.
    // Pre-swizzled source column: ((tid&7) ^ ((tid>>3)&7)) * 8 elements
    // (row&7 == (tid>>3)&7 since p*32 is a multiple of 8).
    const int srow = tid >> 3;                          // 0..31 (+ p*32)
    const int scol = ((tid & 7) ^ (srow & 7)) * 8;      // elements
    // Read-side swizzle (row&7 == c16&7 since wm/wn, mt*16 are multiples of 8):
    const int rsw = (c16 & 7) << 4;

    for (int k0 = 0; k0 < K; k0 += 64) {
        #pragma unroll
        for (int p = 0; p < 4; ++p) {
            gload_lds16(A + (size_t)(m0 + p * 32 + srow) * K + k0 + scol,
                        (char*)As + p * 4096 + tid * 16);
            gload_lds16(Bm + (size_t)(n0 + p * 32 + srow) * K + k0 + scol,
                        (char*)Bs + p * 4096 + tid * 16);
        }
        __syncthreads();
        #pragma unroll
        for (int kk = 0; kk < 2; ++kk) {
            bf16x8 af[4], bf[4];
            #pragma unroll
            for (int mt = 0; mt < 4; ++mt)
                af[mt] = *(const bf16x8*)((const char*)As + (wm + mt * 16 + c16) * 128
                                          + ((kk * 64 + q4 * 16) ^ rsw));
            #pragma unroll
            for (int nt = 0; nt < 4; ++nt)
                bf[nt] = *(const bf16x8*)((const char*)Bs + (wn + nt * 16 + c16) * 128
                                          + ((kk * 64 + q4 * 16) ^ rsw));
            #pragma unroll
            for (int mt = 0; mt < 4; ++mt)
                #pragma unroll
                for (int nt = 0; nt < 4; ++nt)
                    acc[mt][nt] = __builtin_amdgcn_mfma_f32_16x16x32_bf16(af[mt], bf[nt], acc[mt][nt], 0, 0, 0);
        }
        __syncthreads();
    }

    const bool doRope = (MODE == 1) && (n0 < 2048);   // block-uniform
    int ti[4];
    #pragma unroll
    for (int nt = 0; nt < 4; ++nt)
        ti[nt] = ((n0 + wn + nt * 16 + c16) >> 1) & 31;

    #pragma unroll
    for (int mt = 0; mt < 4; ++mt)
        #pragma unroll
        for (int r = 0; r < 4; ++r) {
            const int row = m0 + wm + mt * 16 + q4 * 4 + r;
            float sn[4], cs[4];
            if (doRope) {
                const float2* trow = tab + (size_t)(row & (S_ - 1)) * 32;
                #pragma unroll
                for (int nt = 0; nt < 4; ++nt) {
                    float2 t = trow[ti[nt]];
                    cs[nt] = t.x; sn[nt] = t.y;
                }
            }
            #pragma unroll
            for (int nt = 0; nt < 4; ++nt) {
                const int col = n0 + wn + nt * 16 + c16;
                float v = acc[mt][nt][r];
                if (doRope) {
                    const float partner = __shfl_xor(v, 1, 64);
                    // even col: v = xe, partner = xo -> re = cos*xe - sin*xo
                    // odd  col: v = xo, partner = xe -> ro = sin*xe + cos*xo
                    v = (c16 & 1) ? __builtin_fmaf(sn[nt], partner, cs[nt] * v)
                                  : __builtin_fmaf(cs[nt], v, -sn[nt] * partner);
                }
                if (MODE == 1) ((u16*)Cp)[(size_t)row * N + col] = f2bf(v);
                else           ((float*)Cp)[(size_t)row * N + col] = v;
            }
        }
}

// Balanced schedule: 12 groups per bh, each exactly 44 processes.
__device__ __constant__ signed char g_pairs[32] = {
    11,31, 12,30, 13,29, 14,28, 15,27, 16,26, 17,25, 18,24, 19,23, 20,22,
    10,21, 0,9,  7,8,  5,6,  3,4,  1,2 };
__device__ __constant__ unsigned char g_poff[13] = {0,1,2,3,4,5,6,7,8,9,10,12,16};

// Softmax, no scale/offset: Q pre-scaled by C at cast time; uniform 2^T
// offset cancels in O = (P V)/l. p = exp2(s'), s' <= ~46 -> p <= 8e13 (fp32
// safe); masked entries exp2(-1e30) = 0. Per-lane l partials.
__device__ __forceinline__ void softmax_p(
    f32x4 (&sf)[4], u16* __restrict__ Psw, float& l_i,
    int qrow0, int kt, bool diag, int c16, int q4, bf16x8 (&pf)[2]) {
    if (diag) {
        const int qg = qrow0 + c16;
        #pragma unroll
        for (int nt = 0; nt < 4; ++nt)
            #pragma unroll
            for (int r = 0; r < 4; ++r) {
                int kg = kt * 64 + nt * 16 + q4 * 4 + r;
                if (kg > qg) sf[nt][r] = -1e30f;
            }
    }
    float rs = 0.f;
    #pragma unroll
    for (int nt = 0; nt < 4; ++nt) {
        float p0 = exp2f(sf[nt][0]);
        float p1 = exp2f(sf[nt][1]);
        float p2 = exp2f(sf[nt][2]);
        float p3 = exp2f(sf[nt][3]);
        rs += (p0 + p1) + (p2 + p3);
        uint2 w; w.x = pk2bf(p0, p1); w.y = pk2bf(p2, p3);
        *(uint2*)&Psw[c16 * 72 + nt * 16 + q4 * 4] = w;   // P[qrow][key]
    }
    l_i += rs;
    pf[0] = *(const bf16x8*)&Psw[c16 * 72 + q4 * 8];
    pf[1] = *(const bf16x8*)&Psw[c16 * 72 + 32 + q4 * 8];
}

// Flash attention (unchanged: merged strips, DMA-K with XOR swizzle,
// XCD-chunked grid, per-strip Ps).
__global__ __launch_bounds__(256, 3)
void attn_kernel(const u16* __restrict__ QKV, u16* __restrict__ O) {
    __shared__ u16 Kt[2][64 * 64];
    __shared__ u16 Vt[2][64 * 72];
    __shared__ u16 Ps[8][16 * 72];    // [wave] strip A, [wave+4] strip B
    __shared__ float aS[4][16];
    const int tid = threadIdx.x, lane = tid & 63, wave = tid >> 6;
    const int q4 = lane >> 4, c16 = lane & 15;
    int lin = blockIdx.y * 12 + blockIdx.x;
    int nl = (lin & 7) * 96 + (lin >> 3);
    const int g = nl % 12;
    const int bh = nl / 12;
    const int b = bh >> 4, h = bh & 15;
    const size_t rowbase = (size_t)b * S_ * QKV_N;

    const int kr0 = wave * 16 + (lane >> 3);
    const int kcsw = ((lane & 7) ^ (lane >> 3)) * 8;
    const u16* ksrc0 = QKV + rowbase + (size_t)kr0 * QKV_N + D_MODEL + h * 64 + kcsw;
    const int ksw = (c16 & 7) << 4;
    const int koff0 = (q4 * 16) ^ ksw;
    const int koff1 = (64 + q4 * 16) ^ ksw;

    const int kp = tid & 31, dg = tid >> 5;
    const u16* vbase = QKV + rowbase + (size_t)(2 * kp) * QKV_N + 2 * D_MODEL + h * 64 + dg * 8;

    for (int pi = g_poff[g]; pi < g_poff[g + 1]; ++pi) {
        const int tA = g_pairs[2 * pi], tB = g_pairs[2 * pi + 1];

        bf16x8 qfA[2], qfB[2];
        {
            const u16* qa = QKV + rowbase + (size_t)(tA * 64 + wave * 16 + c16) * QKV_N + h * 64 + q4 * 8;
            qfA[0] = *(const bf16x8*)qa;
            qfA[1] = *(const bf16x8*)(qa + 32);
            const u16* qb = QKV + rowbase + (size_t)(tB * 64 + wave * 16 + c16) * QKV_N + h * 64 + q4 * 8;
            qfB[0] = *(const bf16x8*)qb;
            qfB[1] = *(const bf16x8*)(qb + 32);
        }
        f32x4 ofA[4] = {}, ofB[4] = {};
        float lA = 0.f, lB = 0.f;
        const int qrowA = tA * 64 + wave * 16;
        const int qrowB = tB * 64 + wave * 16;

        gload_lds16(ksrc0, (char*)Kt[0] + wave * 2048 + lane * 16);
        gload_lds16(ksrc0 + (size_t)8 * QKV_N, (char*)Kt[0] + wave * 2048 + 1024 + lane * 16);
        bf16x8 va = *(const bf16x8*)vbase, vb = *(const bf16x8*)(vbase + QKV_N);
        #pragma unroll
        for (int j = 0; j < 8; ++j) {
            u32 w = ((u32)(u16)va[j]) | (((u32)(u16)vb[j]) << 16);
            *(u32*)&Vt[0][(dg * 8 + j) * 72 + 2 * kp] = w;
        }
        __syncthreads();

        int bb = 0;
        for (int kt = 0; kt <= tB; ++kt) {
            const bool more = kt < tB;
            const bool aAct = kt <= tA;
            if (more) {
                const u16* s0 = ksrc0 + (size_t)(kt + 1) * 64 * QKV_N;
                gload_lds16(s0, (char*)Kt[bb ^ 1] + wave * 2048 + lane * 16);
                gload_lds16(s0 + (size_t)8 * QKV_N, (char*)Kt[bb ^ 1] + wave * 2048 + 1024 + lane * 16);
                const u16* vp_ = vbase + (size_t)(kt + 1) * 64 * QKV_N;
                va = *(const bf16x8*)vp_;  vb = *(const bf16x8*)(vp_ + QKV_N);
            }

            f32x4 sfA[4] = {}, sfB[4] = {};
            const char* Kb = (const char*)Kt[bb];
            __builtin_amdgcn_s_setprio(1);
            if (aAct) {
                #pragma unroll
                for (int nt = 0; nt < 4; ++nt) {
                    bf16x8 kf0 = *(const bf16x8*)(Kb + nt * 2048 + c16 * 128 + koff0);
                    bf16x8 kf1 = *(const bf16x8*)(Kb + nt * 2048 + c16 * 128 + koff1);
                    sfB[nt] = __builtin_amdgcn_mfma_f32_16x16x32_bf16(kf0, qfB[0], sfB[nt], 0, 0, 0);
                    sfB[nt] = __builtin_amdgcn_mfma_f32_16x16x32_bf16(kf1, qfB[1], sfB[nt], 0, 0, 0);
                    sfA[nt] = __builtin_amdgcn_mfma_f32_16x16x32_bf16(kf0, qfA[0], sfA[nt], 0, 0, 0);
                    sfA[nt] = __builtin_amdgcn_mfma_f32_16x16x32_bf16(kf1, qfA[1], sfA[nt], 0, 0, 0);
                }
            } else {
                #pragma unroll
                for (int nt = 0; nt < 4; ++nt) {
                    bf16x8 kf0 = *(const bf16x8*)(Kb + nt * 2048 + c16 * 128 + koff0);
                    bf16x8 kf1 = *(const bf16x8*)(Kb + nt * 2048 + c16 * 128 + koff1);
                    sfB[nt] = __builtin_amdgcn_mfma_f32_16x16x32_bf16(kf0, qfB[0], sfB[nt], 0, 0, 0);
                    sfB[nt] = __builtin_amdgcn_mfma_f32_16x16x32_bf16(kf1, qfB[1], sfB[nt], 0, 0, 0);
                }
            }
            __builtin_amdgcn_s_setprio(0);

            bf16x8 pfA[2], pfB[2];
            if (aAct) softmax_p(sfA, Ps[wave], lA, qrowA, kt, kt == tA, c16, q4, pfA);
            softmax_p(sfB, Ps[wave + 4], lB, qrowB, kt, kt == tB, c16, q4, pfB);

            if (more) {
                #pragma unroll
                for (int j = 0; j < 8; ++j) {
                    u32 w = ((u32)(u16)va[j]) | (((u32)(u16)vb[j]) << 16);
                    *(u32*)&Vt[bb ^ 1][(dg * 8 + j) * 72 + 2 * kp] = w;
                }
            }

            const u16* Vb = Vt[bb];
            __builtin_amdgcn_s_setprio(1);
            if (aAct) {
                #pragma unroll
                for (int kk = 0; kk < 2; ++kk)
                    #pragma unroll
                    for (int nt = 0; nt < 4; ++nt) {
                        bf16x8 vf = *(const bf16x8*)&Vb[(nt * 16 + c16) * 72 + kk * 32 + q4 * 8];
                        ofB[nt] = __builtin_amdgcn_mfma_f32_16x16x32_bf16(pfB[kk], vf, ofB[nt], 0, 0, 0);
                        ofA[nt] = __builtin_amdgcn_mfma_f32_16x16x32_bf16(pfA[kk], vf, ofA[nt], 0, 0, 0);
                    }
            } else {
                #pragma unroll
                for (int kk = 0; kk < 2; ++kk)
                    #pragma unroll
                    for (int nt = 0; nt < 4; ++nt) {
                        bf16x8 vf = *(const bf16x8*)&Vb[(nt * 16 + c16) * 72 + kk * 32 + q4 * 8];
                        ofB[nt] = __builtin_amdgcn_mfma_f32_16x16x32_bf16(pfB[kk], vf, ofB[nt], 0, 0, 0);
                    }
            }
            __builtin_amdgcn_s_setprio(0);

            __syncthreads();
            bb ^= 1;
        }

        lA += __shfl_xor(lA, 16, 64); lA += __shfl_xor(lA, 32, 64);
        lB += __shfl_xor(lB, 16, 64); lB += __shfl_xor(lB, 32, 64);
        if (q4 == 0) aS[wave][c16] = lA;
        f32x4 lv = *(const f32x4*)&aS[wave][q4 * 4];
        #pragma unroll
        for (int r = 0; r < 4; ++r) {
            float inv = 1.0f / lv[r];
            int row = b * S_ + tA * 64 + wave * 16 + q4 * 4 + r;
            #pragma unroll
            for (int nt = 0; nt < 4; ++nt)
                O[(size_t)row * D_MODEL + h * 64 + nt * 16 + c16] = f2bf(ofA[nt][r] * inv);
        }
        if (q4 == 0) aS[wave][c16] = lB;
        f32x4 lv2 = *(const f32x4*)&aS[wave][q4 * 4];
        #pragma unroll
        for (int r = 0; r < 4; ++r) {
            float inv = 1.0f / lv2[r];
            int row = b * S_ + tB * 64 + wave * 16 + q4 * 4 + r;
            #pragma unroll
            for (int nt = 0; nt < 4; ++nt)
                O[(size_t)row * D_MODEL + h * 64 + nt * 16 + c16] = f2bf(ofB[nt][r] * inv);
        }
    }
}

extern "C" void kernel_launch(void* const* d_in, const int* in_sizes, int n_in,
                              void* d_out, int out_size, void* d_ws, size_t ws_size,
                              hipStream_t stream) {
    const float* x  = (const float*)d_in[0];
    const int*   tp = (const int*)d_in[1];
    const float* Wq = (const float*)d_in[2];
    const float* Wk = (const float*)d_in[3];
    const float* Wv = (const float*)d_in[4];
    const float* Wo = (const float*)d_in[5];
    float* out = (float*)d_out;

    char* ws = (char*)d_ws;
    u16* xb    = (u16*)(ws);                 // 16,777,216 B
    u16* Wqkvb = (u16*)(ws + 16777216);      //  6,291,456 B
    u16* Wob   = (u16*)(ws + 23068672);      //  2,097,152 B
    u16* QKV   = (u16*)(ws + 25165824);      // 50,331,648 B
    u16* Ob    = (u16*)(ws + 75497472);      // 16,777,216 B  (total 92,274,688 B)
    // RoPE table lives in the first 512 KB of the Ob region: it is consumed
    // only by the qkv GEMM epilogue, which completes before attn writes Ob.
    float2* tab = (float2*)(ws + 75497472);

    cast_all<<<dim3(12544), dim3(256), 0, stream>>>(x, Wq, Wk, Wv, Wo,
                                                    xb, Wqkvb, Wob, tp, tab);

    // qkv projection with fused RoPE in the epilogue.
    gemm_bt<1><<<dim3(QKV_N / 128, ROWS / 128), dim3(256), 0, stream>>>(
        xb, Wqkvb, (void*)QKV, ROWS, QKV_N, D_MODEL, tab);

    attn_kernel<<<dim3(12, B_ * NHEAD), dim3(256), 0, stream>>>(QKV, Ob);

    gemm_bt<0><<<dim3(D_MODEL / 128, ROWS / 128), dim3(256), 0, stream>>>(
        Ob, Wob, (void*)out, ROWS, D_MODEL, D_MODEL, nullptr);
}